// Round 4
// baseline (399.530 us; speedup 1.0000x reference)
//
#include <hip/hip_runtime.h>

#define N_NODES 100000
#define N_EDGES 1280000
#define D 64
#define NB ((N_NODES + 255) / 256)   // 391 scan blocks

// ==================== CSR build ====================

__global__ void hist_kernel(const int* __restrict__ row, int* __restrict__ deg) {
    int e = blockIdx.x * blockDim.x + threadIdx.x;
    if (e < N_EDGES) atomicAdd(&deg[row[e]], 1);
}

// Per-block exclusive scan of deg -> cursor, block totals -> bsum.
__global__ void scan_block_kernel(const int* __restrict__ deg,
                                  int* __restrict__ cursor,
                                  int* __restrict__ bsum) {
    __shared__ int s[256];
    int tid = threadIdx.x;
    int gid = blockIdx.x * 256 + tid;
    int v = (gid < N_NODES) ? deg[gid] : 0;
    s[tid] = v;
    __syncthreads();
    for (int d = 1; d < 256; d <<= 1) {
        int t = (tid >= d) ? s[tid - d] : 0;
        __syncthreads();
        s[tid] += t;
        __syncthreads();
    }
    if (gid < N_NODES) cursor[gid] = s[tid] - v;       // exclusive
    if (tid == 255) bsum[blockIdx.x] = s[255];
}

// Single-block exclusive scan of the NB block sums (NB=391 <= 512).
__global__ void scan_bsum_kernel(int* __restrict__ bsum) {
    __shared__ int s[512];
    int tid = threadIdx.x;
    int v = (tid < NB) ? bsum[tid] : 0;
    s[tid] = v;
    __syncthreads();
    for (int d = 1; d < 512; d <<= 1) {
        int t = (tid >= d) ? s[tid - d] : 0;
        __syncthreads();
        s[tid] += t;
        __syncthreads();
    }
    if (tid < NB) bsum[tid] = s[tid] - v;              // exclusive
}

__global__ void add_offsets_kernel(int* __restrict__ cursor,
                                   const int* __restrict__ bsum) {
    int gid = blockIdx.x * 256 + threadIdx.x;
    if (gid < N_NODES) cursor[gid] += bsum[blockIdx.x];
}

// Scatter edges into CSR order. After this, cursor[r] == END offset of node r
// (start = cursor[r] - deg[r]).
__global__ void scatter_build_kernel(const int* __restrict__ row,
                                     const int* __restrict__ col,
                                     int* __restrict__ cursor,
                                     int* __restrict__ col_sorted) {
    int e = blockIdx.x * blockDim.x + threadIdx.x;
    if (e < N_EDGES) {
        int r = row[e];
        int p = atomicAdd(&cursor[r], 1);
        col_sorted[p] = col[e];
    }
}

// ==================== fused aggregate + mean + dual GEMM ====================
// 4 waves per block, one node per wave.
// Gather phase: lane = s*16+q (s = neighbor sub-lane 0..3, q = feature quad
// 0..15). Each lane float4-loads features [4q,4q+4) of neighbor j+s: 4 edges
// in flight per wave iteration, 16B/lane coalesced (256B per edge row).
// Cross-s reduction via shfl_xor(16/32) butterfly.
// Epilogue: lane f computes out[f]; agg/x rows read as uniform-address
// float4 LDS broadcasts; W/Wr columns read b32 (2-way bank alias = free).
__launch_bounds__(256)
__global__ void aggregate_kernel(const float* __restrict__ x,
                                 const int* __restrict__ cursor_end,
                                 const int* __restrict__ deg,
                                 const int* __restrict__ col_sorted,
                                 const float* __restrict__ W,
                                 const float* __restrict__ Wr,
                                 const float* __restrict__ bias,
                                 float* __restrict__ out) {
    __shared__ float Ws[D * D];
    __shared__ float Wrs[D * D];
    __shared__ float agg_s[4][D];
    __shared__ float x_s[4][D];

    for (int i = threadIdx.x; i < D * D / 4; i += 256) {
        ((float4*)Ws)[i]  = ((const float4*)W)[i];
        ((float4*)Wrs)[i] = ((const float4*)Wr)[i];
    }

    int g = threadIdx.x >> 6;
    int lane = threadIdx.x & 63;
    int s = lane >> 4;           // 0..3 neighbor sub-lane
    int q = lane & 15;           // 0..15 feature quad
    int r = blockIdx.x * 4 + g;  // N_NODES % 4 == 0

    int n = deg[r];
    int start = cursor_end[r] - n;

    float4 acc = make_float4(0.f, 0.f, 0.f, 0.f);
    for (int j = 0; j < n; j += 4) {
        int jj = j + s;
        if (jj < n) {
            int c = col_sorted[start + jj];
            float4 v = *(const float4*)&x[c * D + q * 4];
            acc.x += v.x; acc.y += v.y; acc.z += v.z; acc.w += v.w;
        }
    }
    // butterfly across s: lanes xor 16 then xor 32
    acc.x += __shfl_xor(acc.x, 16, 64);
    acc.y += __shfl_xor(acc.y, 16, 64);
    acc.z += __shfl_xor(acc.z, 16, 64);
    acc.w += __shfl_xor(acc.w, 16, 64);
    acc.x += __shfl_xor(acc.x, 32, 64);
    acc.y += __shfl_xor(acc.y, 32, 64);
    acc.z += __shfl_xor(acc.z, 32, 64);
    acc.w += __shfl_xor(acc.w, 32, 64);

    float inv = 1.0f / (float)(n > 1 ? n : 1);
    if (s == 0) {
        float4 a = make_float4(acc.x * inv, acc.y * inv, acc.z * inv, acc.w * inv);
        *(float4*)&agg_s[g][q * 4] = a;
        *(float4*)&x_s[g][q * 4] = *(const float4*)&x[r * D + q * 4];
    }
    __syncthreads();

    int f = lane;
    float o = bias[f];
    const float4* av = (const float4*)agg_s[g];
    const float4* xv = (const float4*)x_s[g];
#pragma unroll
    for (int k4 = 0; k4 < 16; ++k4) {
        float4 a = av[k4];   // uniform address -> LDS broadcast (1 b128)
        float4 xx = xv[k4];
        int k = k4 * 4;
        o += a.x * Ws[(k + 0) * D + f] + xx.x * Wrs[(k + 0) * D + f];
        o += a.y * Ws[(k + 1) * D + f] + xx.y * Wrs[(k + 1) * D + f];
        o += a.z * Ws[(k + 2) * D + f] + xx.z * Wrs[(k + 2) * D + f];
        o += a.w * Ws[(k + 3) * D + f] + xx.w * Wrs[(k + 3) * D + f];
    }
    out[r * D + f] = o;
}

// ==================== atomic fallback path (needs 400 KB ws) ====================

__global__ void zero_kernel(float* __restrict__ summed, float* __restrict__ cnt) {
    int stride = gridDim.x * blockDim.x;
    int i = blockIdx.x * blockDim.x + threadIdx.x;
    const int total = N_NODES * D;
    for (int idx = i; idx < total; idx += stride) summed[idx] = 0.0f;
    for (int idx = i; idx < N_NODES; idx += stride) cnt[idx] = 0.0f;
}

__global__ void scatter_atomic_kernel(const float* __restrict__ x,
                                      const int* __restrict__ row,
                                      const int* __restrict__ col,
                                      float* __restrict__ summed,
                                      float* __restrict__ cnt) {
    long long gid = (long long)blockIdx.x * blockDim.x + threadIdx.x;
    const long long total = (long long)N_EDGES * D;
    if (gid >= total) return;
    int e = (int)(gid >> 6);
    int f = (int)(gid & 63);
    int r = row[e];
    int c = col[e];
    atomicAdd(&summed[r * D + f], x[c * D + f]);
    if (f == 0) atomicAdd(&cnt[r], 1.0f);
}

__global__ void finish_kernel(const float* __restrict__ x,
                              const float* __restrict__ W,
                              const float* __restrict__ Wr,
                              const float* __restrict__ bias,
                              const float* __restrict__ cnt,
                              float* __restrict__ out) {
    __shared__ float agg_s[4][D];
    __shared__ float x_s[4][D];
    int lrow = threadIdx.x >> 6;
    int f = threadIdx.x & 63;
    int r = blockIdx.x * 4 + lrow;

    float c = cnt[r];
    float inv = 1.0f / fmaxf(c, 1.0f);
    agg_s[lrow][f] = out[r * D + f] * inv;
    x_s[lrow][f] = x[r * D + f];
    __syncthreads();

    float acc = bias[f];
#pragma unroll 8
    for (int k = 0; k < D; ++k) {
        acc += agg_s[lrow][k] * W[k * D + f];
        acc += x_s[lrow][k] * Wr[k * D + f];
    }
    out[r * D + f] = acc;
}

// ==================== launch ====================

extern "C" void kernel_launch(void* const* d_in, const int* in_sizes, int n_in,
                              void* d_out, int out_size, void* d_ws, size_t ws_size,
                              hipStream_t stream) {
    const float* x    = (const float*)d_in[0];
    const int*   ei   = (const int*)d_in[1];   // [2, E]: row = ei, col = ei + E
    const float* W    = (const float*)d_in[2];
    const float* Wr   = (const float*)d_in[3];
    const float* bias = (const float*)d_in[4];
    float* out = (float*)d_out;

    const int* row = ei;
    const int* col = ei + N_EDGES;

    // CSR workspace layout: deg(N) | cursor(N) | bsum(512) | col_sorted(E)
    const size_t need_csr = (size_t)2 * N_NODES * 4 + 2048 + (size_t)N_EDGES * 4;

    if (ws_size >= need_csr) {
        char* ws = (char*)d_ws;
        int* deg        = (int*)(ws);
        int* cursor     = (int*)(ws + (size_t)1 * N_NODES * 4);
        int* bsum       = (int*)(ws + (size_t)2 * N_NODES * 4);
        int* col_sorted = (int*)(ws + (size_t)2 * N_NODES * 4 + 2048);

        hipMemsetAsync(deg, 0, (size_t)N_NODES * 4, stream);
        hist_kernel<<<(N_EDGES + 255) / 256, 256, 0, stream>>>(row, deg);
        scan_block_kernel<<<NB, 256, 0, stream>>>(deg, cursor, bsum);
        scan_bsum_kernel<<<1, 512, 0, stream>>>(bsum);
        add_offsets_kernel<<<NB, 256, 0, stream>>>(cursor, bsum);
        scatter_build_kernel<<<(N_EDGES + 255) / 256, 256, 0, stream>>>(row, col, cursor, col_sorted);
        aggregate_kernel<<<N_NODES / 4, 256, 0, stream>>>(x, cursor, deg, col_sorted, W, Wr, bias, out);
    } else {
        // atomic fallback (round-1 verified): out doubles as summed[]
        float* cnt = (float*)d_ws;   // N_NODES floats
        zero_kernel<<<4096, 256, 0, stream>>>(out, cnt);
        long long total = (long long)N_EDGES * D;
        int blocks = (int)((total + 255) / 256);
        scatter_atomic_kernel<<<blocks, 256, 0, stream>>>(x, row, col, out, cnt);
        finish_kernel<<<(N_NODES + 3) / 4, 256, 0, stream>>>(x, W, Wr, bias, cnt, out);
    }
}

// Round 5
// 333.798 us; speedup vs baseline: 1.1969x; 1.1969x over previous
//
#include <hip/hip_runtime.h>

#define N_NODES 100000
#define N_EDGES 1280000
#define D 64
#define NB ((N_NODES + 255) / 256)   // 391 scan blocks

// ==================== CSR build ====================

// 4 edges per thread via int4 (N_EDGES % 4 == 0).
__global__ void hist_kernel(const int4* __restrict__ row4, int* __restrict__ deg) {
    int t = blockIdx.x * blockDim.x + threadIdx.x;
    if (t < N_EDGES / 4) {
        int4 r = row4[t];
        atomicAdd(&deg[r.x], 1);
        atomicAdd(&deg[r.y], 1);
        atomicAdd(&deg[r.z], 1);
        atomicAdd(&deg[r.w], 1);
    }
}

// Per-block exclusive scan of deg -> cursor, raw block totals -> bsum.
__global__ void scan_block_kernel(const int* __restrict__ deg,
                                  int* __restrict__ cursor,
                                  int* __restrict__ bsum) {
    __shared__ int s[256];
    int tid = threadIdx.x;
    int gid = blockIdx.x * 256 + tid;
    int v = (gid < N_NODES) ? deg[gid] : 0;
    s[tid] = v;
    __syncthreads();
    for (int d = 1; d < 256; d <<= 1) {
        int t = (tid >= d) ? s[tid - d] : 0;
        __syncthreads();
        s[tid] += t;
        __syncthreads();
    }
    if (gid < N_NODES) cursor[gid] = s[tid] - v;       // block-local exclusive
    if (tid == 255) bsum[blockIdx.x] = s[255];
}

// Fused: block b reduces sum(bsum_raw[0..b)) itself, then adds to cursor.
__global__ void add_offsets_kernel(int* __restrict__ cursor,
                                   const int* __restrict__ bsum_raw) {
    __shared__ int red[256];
    int tid = threadIdx.x;
    int b = blockIdx.x;
    int sum = 0;
    for (int i = tid; i < b; i += 256) sum += bsum_raw[i];
    red[tid] = sum;
    __syncthreads();
    for (int off = 128; off > 0; off >>= 1) {
        if (tid < off) red[tid] += red[tid + off];
        __syncthreads();
    }
    int gid = b * 256 + tid;
    if (gid < N_NODES) cursor[gid] += red[0];
}

// Scatter edges into CSR order; 4 edges per thread. After this,
// cursor[r] == END offset of node r (start = cursor[r] - deg[r]).
__global__ void scatter_build_kernel(const int4* __restrict__ row4,
                                     const int4* __restrict__ col4,
                                     int* __restrict__ cursor,
                                     int* __restrict__ col_sorted) {
    int t = blockIdx.x * blockDim.x + threadIdx.x;
    if (t < N_EDGES / 4) {
        int4 r = row4[t];
        int4 c = col4[t];
        col_sorted[atomicAdd(&cursor[r.x], 1)] = c.x;
        col_sorted[atomicAdd(&cursor[r.y], 1)] = c.y;
        col_sorted[atomicAdd(&cursor[r.z], 1)] = c.z;
        col_sorted[atomicAdd(&cursor[r.w], 1)] = c.w;
    }
}

// ==================== fused aggregate + mean + dual GEMM ====================
// 512 threads = 8 waves; each wave processes 4 nodes sequentially (32/block,
// 3125 blocks). LDS = 32K (W,Wr) + 4K (agg/x rows) = 36K -> 4 blocks/CU ->
// 32 waves/CU (100% occupancy at <=64 VGPR).
// Gather per node: preload up to 64 col indices with ONE coalesced load,
// broadcast via shfl (no memory op), then issue independent float4 x-loads
// back-to-back (lane = s*16+q: 4 neighbors in flight, 16B/lane).
// Epilogue per node (wave-private, no block barrier): lane f computes
// out[f] = bias[f] + sum_k agg[k]*W[k][f] + x[k]*Wr[k][f].
__launch_bounds__(512, 8)
__global__ void aggregate_kernel(const float* __restrict__ x,
                                 const int* __restrict__ cursor_end,
                                 const int* __restrict__ deg,
                                 const int* __restrict__ col_sorted,
                                 const float* __restrict__ W,
                                 const float* __restrict__ Wr,
                                 const float* __restrict__ bias,
                                 float* __restrict__ out) {
    __shared__ float Ws[D * D];
    __shared__ float Wrs[D * D];
    __shared__ float agg_s[8][D];
    __shared__ float x_s[8][D];

    for (int i = threadIdx.x; i < D * D / 4; i += 512) {
        ((float4*)Ws)[i]  = ((const float4*)W)[i];
        ((float4*)Wrs)[i] = ((const float4*)Wr)[i];
    }
    __syncthreads();   // Ws/Wrs visible to all waves; only block-wide barrier

    int wv = threadIdx.x >> 6;
    int lane = threadIdx.x & 63;
    int s = lane >> 4;            // 0..3 neighbor sub-lane
    int q = lane & 15;            // 0..15 feature quad
    float bf = bias[lane];        // per-lane constant across nodes

    int node0 = (blockIdx.x * 8 + wv) * 4;   // 100000 = 3125*32: always in range

#pragma unroll 1
    for (int nn = 0; nn < 4; ++nn) {
        int r = node0 + nn;
        int n = deg[r];
        int start = cursor_end[r] - n;

        float4 acc = make_float4(0.f, 0.f, 0.f, 0.f);
        for (int base = 0; base < n; base += 64) {
            int m = n - base; if (m > 64) m = 64;
            int idx = 0;
            if (lane < m) idx = col_sorted[start + base + lane];  // 1 coalesced load
            for (int j = 0; j < m; j += 4) {
                int jj = j + s;
                int c = __shfl(idx, jj, 64);                      // VALU broadcast
                if (jj < m) {
                    float4 v = *(const float4*)&x[(size_t)c * D + q * 4];
                    acc.x += v.x; acc.y += v.y; acc.z += v.z; acc.w += v.w;
                }
            }
        }
        // butterfly across s (bits 4,5): every lane ends with its quad's total
        acc.x += __shfl_xor(acc.x, 16, 64);
        acc.y += __shfl_xor(acc.y, 16, 64);
        acc.z += __shfl_xor(acc.z, 16, 64);
        acc.w += __shfl_xor(acc.w, 16, 64);
        acc.x += __shfl_xor(acc.x, 32, 64);
        acc.y += __shfl_xor(acc.y, 32, 64);
        acc.z += __shfl_xor(acc.z, 32, 64);
        acc.w += __shfl_xor(acc.w, 32, 64);

        float inv = 1.0f / (float)(n > 1 ? n : 1);
        if (lane < 16) {   // s==0 group covers quads 0..15
            float4 a = make_float4(acc.x * inv, acc.y * inv, acc.z * inv, acc.w * inv);
            *(float4*)&agg_s[wv][q * 4] = a;
            *(float4*)&x_s[wv][q * 4] = *(const float4*)&x[(size_t)r * D + q * 4];
        }
        // wave-private LDS rows; DS ops are in-order per wave. Pin compiler order:
        __builtin_amdgcn_wave_barrier();

        int f = lane;
        float o = bf;
        const float4* av = (const float4*)agg_s[wv];
        const float4* xv = (const float4*)x_s[wv];
#pragma unroll
        for (int k4 = 0; k4 < 16; ++k4) {
            float4 a = av[k4];    // uniform address -> LDS broadcast
            float4 xx = xv[k4];
            int k = k4 * 4;
            o += a.x * Ws[(k + 0) * D + f] + xx.x * Wrs[(k + 0) * D + f];
            o += a.y * Ws[(k + 1) * D + f] + xx.y * Wrs[(k + 1) * D + f];
            o += a.z * Ws[(k + 2) * D + f] + xx.z * Wrs[(k + 2) * D + f];
            o += a.w * Ws[(k + 3) * D + f] + xx.w * Wrs[(k + 3) * D + f];
        }
        out[(size_t)r * D + f] = o;
        __builtin_amdgcn_wave_barrier();   // keep next node's writes after these reads
    }
}

// ==================== atomic fallback path (needs 400 KB ws) ====================

__global__ void zero_kernel(float* __restrict__ summed, float* __restrict__ cnt) {
    int stride = gridDim.x * blockDim.x;
    int i = blockIdx.x * blockDim.x + threadIdx.x;
    const int total = N_NODES * D;
    for (int idx = i; idx < total; idx += stride) summed[idx] = 0.0f;
    for (int idx = i; idx < N_NODES; idx += stride) cnt[idx] = 0.0f;
}

__global__ void scatter_atomic_kernel(const float* __restrict__ x,
                                      const int* __restrict__ row,
                                      const int* __restrict__ col,
                                      float* __restrict__ summed,
                                      float* __restrict__ cnt) {
    long long gid = (long long)blockIdx.x * blockDim.x + threadIdx.x;
    const long long total = (long long)N_EDGES * D;
    if (gid >= total) return;
    int e = (int)(gid >> 6);
    int f = (int)(gid & 63);
    int r = row[e];
    int c = col[e];
    atomicAdd(&summed[r * D + f], x[c * D + f]);
    if (f == 0) atomicAdd(&cnt[r], 1.0f);
}

__global__ void finish_kernel(const float* __restrict__ x,
                              const float* __restrict__ W,
                              const float* __restrict__ Wr,
                              const float* __restrict__ bias,
                              const float* __restrict__ cnt,
                              float* __restrict__ out) {
    __shared__ float agg_s[4][D];
    __shared__ float x_s[4][D];
    int lrow = threadIdx.x >> 6;
    int f = threadIdx.x & 63;
    int r = blockIdx.x * 4 + lrow;

    float c = cnt[r];
    float inv = 1.0f / fmaxf(c, 1.0f);
    agg_s[lrow][f] = out[r * D + f] * inv;
    x_s[lrow][f] = x[r * D + f];
    __syncthreads();

    float acc = bias[f];
#pragma unroll 8
    for (int k = 0; k < D; ++k) {
        acc += agg_s[lrow][k] * W[k * D + f];
        acc += x_s[lrow][k] * Wr[k * D + f];
    }
    out[r * D + f] = acc;
}

// ==================== launch ====================

extern "C" void kernel_launch(void* const* d_in, const int* in_sizes, int n_in,
                              void* d_out, int out_size, void* d_ws, size_t ws_size,
                              hipStream_t stream) {
    const float* x    = (const float*)d_in[0];
    const int*   ei   = (const int*)d_in[1];   // [2, E]: row = ei, col = ei + E
    const float* W    = (const float*)d_in[2];
    const float* Wr   = (const float*)d_in[3];
    const float* bias = (const float*)d_in[4];
    float* out = (float*)d_out;

    const int* row = ei;
    const int* col = ei + N_EDGES;

    // CSR workspace layout: deg(N) | cursor(N) | bsum(512) | col_sorted(E)
    const size_t need_csr = (size_t)2 * N_NODES * 4 + 2048 + (size_t)N_EDGES * 4;

    if (ws_size >= need_csr) {
        char* ws = (char*)d_ws;
        int* deg        = (int*)(ws);
        int* cursor     = (int*)(ws + (size_t)1 * N_NODES * 4);
        int* bsum       = (int*)(ws + (size_t)2 * N_NODES * 4);
        int* col_sorted = (int*)(ws + (size_t)2 * N_NODES * 4 + 2048);

        hipMemsetAsync(deg, 0, (size_t)N_NODES * 4, stream);
        hist_kernel<<<(N_EDGES / 4 + 255) / 256, 256, 0, stream>>>((const int4*)row, deg);
        scan_block_kernel<<<NB, 256, 0, stream>>>(deg, cursor, bsum);
        add_offsets_kernel<<<NB, 256, 0, stream>>>(cursor, bsum);
        scatter_build_kernel<<<(N_EDGES / 4 + 255) / 256, 256, 0, stream>>>(
            (const int4*)row, (const int4*)col, cursor, col_sorted);
        aggregate_kernel<<<N_NODES / 32, 512, 0, stream>>>(x, cursor, deg, col_sorted, W, Wr, bias, out);
    } else {
        // atomic fallback (round-1 verified): out doubles as summed[]
        float* cnt = (float*)d_ws;   // N_NODES floats
        zero_kernel<<<4096, 256, 0, stream>>>(out, cnt);
        long long total = (long long)N_EDGES * D;
        int blocks = (int)((total + 255) / 256);
        scatter_atomic_kernel<<<blocks, 256, 0, stream>>>(x, row, col, out, cnt);
        finish_kernel<<<(N_NODES + 3) / 4, 256, 0, stream>>>(x, W, Wr, bias, cnt, out);
    }
}